// Round 9
// baseline (673.329 us; speedup 1.0000x reference)
//
#include <hip/hip_runtime.h>
#include <math.h>

#define BB 8
#define LL 4096
#define DD 512
#define PTOT (BB*LL)      // 32768 positions
#define HID  2048

typedef __attribute__((ext_vector_type(8))) short short8;   // 8 bf16 (4 VGPRs)
typedef __attribute__((ext_vector_type(4))) float f32x4;

typedef __attribute__((address_space(1))) const unsigned int gconst_u32;
typedef __attribute__((address_space(3))) unsigned int lds_u32;

__device__ __forceinline__ void gload16(const void* g, void* l) {
    // async global->LDS DMA, 16B per lane; LDS dest = wave-uniform base + lane*16
    __builtin_amdgcn_global_load_lds((gconst_u32*)g, (lds_u32*)l, 16, 0, 0);
}

__device__ __forceinline__ unsigned short f2bf(float f) {
    union { float f; unsigned int u; } v; v.f = f;
    unsigned int r = v.u + 0x7fffu + ((v.u >> 16) & 1u);
    return (unsigned short)(r >> 16);
}
__device__ __forceinline__ float bf2f(unsigned short h) {
    union { unsigned int u; float f; } v; v.u = ((unsigned int)h) << 16;
    return v.f;
}
__device__ __forceinline__ float gelu_fast(float x) {
    float x2 = x * x;
    float t  = x * fmaf(0.044715f, x2, 1.0f);
    float e  = __builtin_amdgcn_exp2f(-2.3021143f * t);   // e^{-2z}
    return x * __builtin_amdgcn_rcpf(1.0f + e);
}

__device__ __forceinline__ void barrier_sync() {
    asm volatile("" ::: "memory");
    __builtin_amdgcn_s_barrier();
    asm volatile("" ::: "memory");
}
#define WAITV(N) asm volatile("s_waitcnt vmcnt(" #N ")" ::: "memory")
#define WAITL0() asm volatile("s_waitcnt lgkmcnt(0)" ::: "memory")
#define SCHED0() __builtin_amdgcn_sched_barrier(0)

// ---------------------------------------------------------------------------
// x fp32 -> bf16; also zero the 256B zero-page (ws is re-poisoned each launch)
__global__ __launch_bounds__(256) void convert_x(const float* __restrict__ x,
                                                 unsigned short* __restrict__ xb,
                                                 unsigned short* __restrict__ zp) {
    int tid = blockIdx.x * 256 + threadIdx.x;
    if (blockIdx.x == 0 && threadIdx.x < 128) zp[threadIdx.x] = 0;
    float4 v = ((const float4*)x)[tid];
    uint2 o;
    o.x = (unsigned int)f2bf(v.x) | ((unsigned int)f2bf(v.y) << 16);
    o.y = (unsigned int)f2bf(v.z) | ((unsigned int)f2bf(v.w) << 16);
    ((uint2*)xb)[tid] = o;
}

// conv W (o,c,k) -> Wt[o][k*512+c] bf16
__global__ __launch_bounds__(256) void trans_wconv(const float* __restrict__ W,
                                                   unsigned short* __restrict__ Wt, int K) {
    int tid = blockIdx.x * 256 + threadIdx.x;
    if (tid >= DD * DD * K) return;
    int o  = tid / (K * DD);
    int kc = tid - o * K * DD;
    int k  = kc >> 9;
    int c  = kc & (DD - 1);
    Wt[tid] = f2bf(W[(o * DD + c) * K + k]);
}

// mlp_w1 (c, n) -> W1t[n][c]
__global__ __launch_bounds__(256) void trans_w1(const float* __restrict__ W,
                                                unsigned short* __restrict__ Wt) {
    int tid = blockIdx.x * 256 + threadIdx.x;   // n*512 + c
    int n = tid >> 9;
    int c = tid & (DD - 1);
    Wt[tid] = f2bf(W[c * HID + n]);
}

// mlp_w2 (h, n) -> W2t[n][h]
__global__ __launch_bounds__(256) void trans_w2(const float* __restrict__ W,
                                                unsigned short* __restrict__ Wt) {
    int tid = blockIdx.x * 256 + threadIdx.x;   // n*2048 + h
    int n = tid >> 11;
    int h = tid & (HID - 1);
    Wt[tid] = f2bf(W[h * DD + n]);
}

// srcp[p*K + k] = p + k - pad if in-range and chain matches, else -1
__global__ __launch_bounds__(256) void make_srcp(const int* __restrict__ chain,
                                                 int* __restrict__ srcp, int K) {
    int tid = blockIdx.x * 256 + threadIdx.x;
    if (tid >= PTOT * K) return;
    int p = tid / K;
    int k = tid - p * K;
    int b = p >> 12;
    int l = p & (LL - 1);
    int pad = (K - 1) >> 1;
    int l2 = l + k - pad;
    bool ok = (l2 >= 0) && (l2 < LL) && (chain[b * LL + l2] == chain[b * LL + l]);
    srcp[tid] = ok ? (p + k - pad) : -1;
}

// ---------------------------------------------------------------------------
// 256x256 MFMA GEMM, cross-phase rotation with BARRIER-LEVEL retirement
// invariant (round 9; fixes round 8's cross-wave vmcnt race).
// vmcnt is PER-WAVE: a read of rows staged by OTHER waves is only safe if,
// at some earlier barrier, EVERY wave had retired those streams. Invariants:
//   end-P1(kt) barrier: all waves retired A0,B0(kt+1)   [WAITV(4) in P1]
//   end-P2(kt) barrier: all waves retired A1,B1(kt+1)   [WAITV(8) in P2]
// => P2's pre-reads (A0,B0 of kt+1) and P1's reads (B1,A1 of kt) are always
// covered by a prior barrier, not just the reader's own counter.
// Steady state per wave: enter P1(kt) with 8 outstanding (tile kt+1);
// P1 retires 4; P2 issues 8 (tile kt+2, after its ds_reads - round-6 rule:
// ds_read must precede gload16 in-phase), retires 4 (12->8). Induction from
// prologue: stage tiles 0,1; WAITV(8) retires tile 0 fully; barrier.
// Tail: P2(NKT-2) stages clip to 0 => WAITV(0) there; last tile: no waits.
// Slot overwrite margins (DMA for tile kt+2 issued P2(kt), buffer kt&1):
// A0,B0: pre-read P2(kt-1), drained, +1 bar; A1,B1: read P1(kt), drained,
// +1 bar (no reads of buffer kt&1 occur in P2). Safe.
// Rotation: af A0(kt)->A1(kt)->A0(kt+1); bf0 B0(kt)->B0(kt+1); bf1 B1(kt).
// Q clusters never wait: operands pre-read in an earlier phase. Reads issue
// after MFMAs (SCHED0 pins WAR points; sequential lifetimes, no VGPR growth).
// EPI: 0 bf16=acc+bias; 1 bf16=gelu(acc+bias); 2 f32=acc+bias; 3 f32+=acc.
template <int TAPS, int EPI>
__global__ __launch_bounds__(512) void mfma_gemm8(
        const unsigned short* __restrict__ A, int lda,
        const int* __restrict__ srcp,
        const unsigned short* __restrict__ Bt, int ldb,
        const float* __restrict__ bias,
        void* __restrict__ Yv, int ldc, int Kspan,
        const unsigned short* __restrict__ zp) {
    __shared__ alignas(16) unsigned short As[2 * 256 * 64];   // 64 KB
    __shared__ alignas(16) unsigned short Bs[2 * 256 * 64];   // 64 KB
    __shared__ int srcp_s[TAPS > 0 ? 256 * TAPS : 4];         // <=7 KB

    const int t = threadIdx.x;
    const int lane = t & 63, w = t >> 6;
    const int wr = w & 1, wc = w >> 1;          // 2M x 4N waves
    const int lm = lane & 15, qh = lane >> 4, x7 = lane & 7;
    const int qq = (lane & 7) ^ (lane >> 3);    // staged source quad (swizzle)
    const int l3 = lane >> 3;                   // row-within-8
    const int p0 = blockIdx.x * 256;
    const int o0 = blockIdx.y * 256;
    const int NKT = TAPS ? TAPS * 8 : (Kspan >> 6);

    f32x4 acc[8][4];
#pragma unroll
    for (int mi = 0; mi < 8; mi++)
#pragma unroll
        for (int nj = 0; nj < 4; nj++) acc[mi][nj] = (f32x4){0.f, 0.f, 0.f, 0.f};

    // stream h: tile jt=h>>2 (buffer jt&1); h&1: 0=A,1=B; h&2: row half
    auto stgB = [&](int h) {
        if (h >= 4 * NKT) return;
        int jt = h >> 2;
        int rb = (h & 2) ? 128 : 0;
        unsigned short* dst = Bs + (jt & 1) * 16384 + (rb + w * 16) * 64;
        int kb = jt << 6;
#pragma unroll
        for (int i = 0; i < 2; i++) {
            int rl = rb + w * 16 + i * 8 + l3;
            gload16(Bt + (size_t)(o0 + rl) * ldb + kb + qq * 8, dst + i * 512);
        }
    };
    auto stgA = [&](int h, int sp0, int sp1) {
        if (h >= 4 * NKT) return;
        int jt = h >> 2;
        int rb = (h & 2) ? 128 : 0;
        unsigned short* dst = As + (jt & 1) * 16384 + (rb + w * 16) * 64;
#pragma unroll
        for (int i = 0; i < 2; i++) {
            const unsigned short* g;
            if (TAPS) {
                int sp = i ? sp1 : sp0;
                g = (sp >= 0) ? (A + (size_t)sp * lda + (jt & 7) * 64 + qq * 8) : zp;
            } else {
                int rl = rb + w * 16 + i * 8 + l3;
                g = A + (size_t)(p0 + rl) * lda + (jt << 6) + qq * 8;
            }
            gload16(g, dst + i * 512);
        }
    };
    auto ldsp = [&](int h, int& sp0, int& sp1) {   // prefetch gather rows for A-stream h
        if (TAPS && h < 4 * NKT) {
            int jt = h >> 2, tap = jt >> 3;
            int rb = (h & 2) ? 128 : 0;
            int rl = rb + w * 16 + l3;
            sp0 = srcp_s[rl * TAPS + tap];
            sp1 = srcp_s[(rl + 8) * TAPS + tap];
        }
    };

    // prologue: stage tiles 0 and 1 (streams 0..7, order A0,B0,A1,B1 per tile)
    if (TAPS) {
        for (int idx = t; idx < 256 * TAPS; idx += 512)
            srcp_s[idx] = srcp[(size_t)p0 * TAPS + idx];
    }
    __syncthreads();                       // drains vmcnt -> clean counter base
    int sp0 = -1, sp1 = -1, sp2 = -1, sp3 = -1;
    ldsp(0, sp0, sp1); stgA(0, sp0, sp1); stgB(1);
    ldsp(2, sp0, sp1); stgA(2, sp0, sp1); stgB(3);
    ldsp(4, sp0, sp1); stgA(4, sp0, sp1); stgB(5);
    ldsp(6, sp0, sp1); stgA(6, sp0, sp1); stgB(7);
    WAITV(8);                              // retire ALL of tile 0 (own 8 instr)
    barrier_sync();                        // => every wave's tile 0 landed

#define RD_A(AF, MIH, BASE) do {                                                \
    _Pragma("unroll")                                                           \
    for (int kk = 0; kk < 2; kk++) {                                            \
        int sa = ((kk * 4 + qh) ^ x7) * 8;                                      \
        _Pragma("unroll")                                                       \
        for (int m = 0; m < 4; m++)                                             \
            AF[m][kk] = *(const short8*)&(BASE)[((((MIH)*4+m)*2 + wr)*16 + lm)*64 + sa]; \
    } } while (0)
#define RD_B(BF, NJH, BASE) do {                                                \
    _Pragma("unroll")                                                           \
    for (int kk = 0; kk < 2; kk++) {                                            \
        int sa = ((kk * 4 + qh) ^ x7) * 8;                                      \
        _Pragma("unroll")                                                       \
        for (int n = 0; n < 2; n++)                                             \
            BF[n][kk] = *(const short8*)&(BASE)[((((NJH)*2+n)*4 + wc)*16 + lm)*64 + sa]; \
    } } while (0)
#define MFMA_Q(AF, MIH, BF, NJH)                                                \
    __builtin_amdgcn_s_setprio(1);                                              \
    _Pragma("unroll")                                                           \
    for (int kk = 0; kk < 2; kk++)                                              \
        _Pragma("unroll")                                                       \
        for (int m = 0; m < 4; m++)                                             \
            _Pragma("unroll")                                                   \
            for (int n = 0; n < 2; n++)                                         \
                acc[(MIH)*4+m][(NJH)*2+n] = __builtin_amdgcn_mfma_f32_16x16x32_bf16( \
                    AF[m][kk], BF[n][kk], acc[(MIH)*4+m][(NJH)*2+n], 0, 0, 0);  \
    __builtin_amdgcn_s_setprio(0)

    short8 af[4][2], bf0[2][2], bf1[2][2];
    // pre-read tile 0's P1 operands (tile 0 fully landed at prologue barrier)
    RD_A(af, 0, As);
    RD_B(bf0, 0, Bs);

#pragma unroll 1
    for (int kt = 0; kt < NKT; ++kt) {
        const unsigned short* as_  = As + (kt & 1) * 16384;
        const unsigned short* bs_  = Bs + (kt & 1) * 16384;
        const unsigned short* as2_ = As + ((kt + 1) & 1) * 16384;
        const unsigned short* bs2_ = Bs + ((kt + 1) & 1) * 16384;
        const bool last = (kt == NKT - 1);
        // ---- P1: rd bf1<-B1(kt) | Q(0,0) zero-wait | Q(0,1) | rd af<-A1(kt)
        //          | WAITV(4): retire own A0,B0(kt+1) | lgkm0 | bar
        RD_B(bf1, 1, bs_);                 // safe: tile kt landed @ prev barrier
        MFMA_Q(af, 0, bf0, 0);
        MFMA_Q(af, 0, bf1, 1);
        SCHED0();                          // pin af rotation below Qs
        RD_A(af, 1, as_);                  // af <- A1(kt)
        if (!last) {
            ldsp(4 * kt + 8, sp0, sp1);    // gather rows for A0(kt+2)
            ldsp(4 * kt + 10, sp2, sp3);   // gather rows for A1(kt+2)
            WAITV(4);                      // -> barrier guarantees A0,B0(kt+1)
        }
        WAITL0();
        barrier_sync();
        // ---- P2: Q(1,0),Q(1,1) zero-wait | pre-rd A0,B0(kt+1) | stage kt+2
        //          | WAITV(8): retire own A1,B1(kt+1) | lgkm0 | bar
        MFMA_Q(af, 1, bf0, 0);
        MFMA_Q(af, 1, bf1, 1);
        SCHED0();                          // pin pre-reads below Qs
        if (!last) {
            RD_A(af, 0, as2_);             // af  <- A0(kt+1)  [covered by bar]
            RD_B(bf0, 0, bs2_);            // bf0 <- B0(kt+1)
            stgA(4 * kt + 8, sp0, sp1);    // A0(kt+2)   (ds_reads before DMAs)
            stgB(4 * kt + 9);              // B0(kt+2)
            stgA(4 * kt + 10, sp2, sp3);   // A1(kt+2)
            stgB(4 * kt + 11);             // B1(kt+2)
            if (kt == NKT - 2) { WAITV(0); } else { WAITV(8); }
        }
        WAITL0();
        barrier_sync();
    }
#undef RD_A
#undef RD_B
#undef MFMA_Q

    // epilogue: C/D layout col=lane&15, row=(lane>>4)*4+reg  [m89-verified]
#pragma unroll
    for (int mi = 0; mi < 8; mi++) {
#pragma unroll
        for (int nj = 0; nj < 4; nj++) {
            int col = o0 + (nj * 4 + wc) * 16 + lm;
#pragma unroll
            for (int r = 0; r < 4; r++) {
                int row = p0 + (mi * 2 + wr) * 16 + qh * 4 + r;
                float v = acc[mi][nj][r];
                size_t idx = (size_t)row * ldc + col;
                if (EPI == 0) {
                    ((unsigned short*)Yv)[idx] = f2bf(v + bias[col]);
                } else if (EPI == 1) {
                    ((unsigned short*)Yv)[idx] = f2bf(gelu_fast(v + bias[col]));
                } else if (EPI == 2) {
                    ((float*)Yv)[idx] = v + bias[col];
                } else {
                    ((float*)Yv)[idx] += v;
                }
            }
        }
    }
}

// ---------------------------------------------------------------------------
// LN1: out_bf16 = LN(x_f32 + conv_bf16)
__global__ __launch_bounds__(256) void ln1_kernel(const float* __restrict__ x,
                                                  const unsigned short* __restrict__ conv,
                                                  const float* __restrict__ g,
                                                  const float* __restrict__ beta,
                                                  unsigned short* __restrict__ h) {
    int p = blockIdx.x, t = threadIdx.x;
    size_t base = (size_t)p * DD;
    float v0 = x[base + t] + bf2f(conv[base + t]);
    float v1 = x[base + 256 + t] + bf2f(conv[base + 256 + t]);
    float s = v0 + v1, sq = v0 * v0 + v1 * v1;
#pragma unroll
    for (int off = 32; off > 0; off >>= 1) { s += __shfl_xor(s, off); sq += __shfl_xor(sq, off); }
    __shared__ float red[2][4];
    int wid = t >> 6, lane = t & 63;
    if (lane == 0) { red[0][wid] = s; red[1][wid] = sq; }
    __syncthreads();
    float S = red[0][0] + red[0][1] + red[0][2] + red[0][3];
    float SQ = red[1][0] + red[1][1] + red[1][2] + red[1][3];
    float mu = S * (1.f / DD);
    float var = SQ * (1.f / DD) - mu * mu;
    float rs = rsqrtf(var + 1e-5f);
    h[base + t]       = f2bf((v0 - mu) * rs * g[t] + beta[t]);
    h[base + 256 + t] = f2bf((v1 - mu) * rs * g[256 + t] + beta[256 + t]);
}

// LN2: out_f32 = LN(h_bf16 + out_f32) in place
__global__ __launch_bounds__(256) void ln2_kernel(const unsigned short* __restrict__ h,
                                                  float* __restrict__ out,
                                                  const float* __restrict__ g,
                                                  const float* __restrict__ beta) {
    int p = blockIdx.x, t = threadIdx.x;
    size_t base = (size_t)p * DD;
    float v0 = bf2f(h[base + t]) + out[base + t];
    float v1 = bf2f(h[base + 256 + t]) + out[base + 256 + t];
    float s = v0 + v1, sq = v0 * v0 + v1 * v1;
#pragma unroll
    for (int off = 32; off > 0; off >>= 1) { s += __shfl_xor(s, off); sq += __shfl_xor(sq, off); }
    __shared__ float red[2][4];
    int wid = t >> 6, lane = t & 63;
    if (lane == 0) { red[0][wid] = s; red[1][wid] = sq; }
    __syncthreads();
    float S = red[0][0] + red[0][1] + red[0][2] + red[0][3];
    float SQ = red[1][0] + red[1][1] + red[1][2] + red[1][3];
    float mu = S * (1.f / DD);
    float var = SQ * (1.f / DD) - mu * mu;
    float rs = rsqrtf(var + 1e-5f);
    out[base + t]       = (v0 - mu) * rs * g[t] + beta[t];
    out[base + 256 + t] = (v1 - mu) * rs * g[256 + t] + beta[256 + t];
}

// ---------------------------------------------------------------------------
extern "C" void kernel_launch(void* const* d_in, const int* in_sizes, int n_in,
                              void* d_out, int out_size, void* d_ws, size_t ws_size,
                              hipStream_t stream) {
    const float* x     = (const float*)d_in[0];
    const int*   chain = (const int*)d_in[1];
    const float* W3    = (const float*)d_in[2];
    const float* b3    = (const float*)d_in[3];
    const float* W5    = (const float*)d_in[4];
    const float* b5    = (const float*)d_in[5];
    const float* W7    = (const float*)d_in[6];
    const float* b7    = (const float*)d_in[7];
    const float* w1    = (const float*)d_in[8];
    const float* bm1   = (const float*)d_in[9];
    const float* w2    = (const float*)d_in[10];
    const float* bm2   = (const float*)d_in[11];
    const float* g1    = (const float*)d_in[12];
    const float* be1   = (const float*)d_in[13];
    const float* g2    = (const float*)d_in[14];
    const float* be2   = (const float*)d_in[15];
    float* out = (float*)d_out;

    const size_t ACT = (size_t)PTOT * DD * 2;     // 32 MB bf16 activation buffer
    char* ws = (char*)d_ws;
    size_t off = 0;
    unsigned short* Xb   = (unsigned short*)(ws + off); off += ACT;
    unsigned short* buf1 = (unsigned short*)(ws + off); off += ACT;
    unsigned short* buf2 = (unsigned short*)(ws + off); off += ACT;
    unsigned short* w3t  = (unsigned short*)(ws + off); off += (size_t)3 * DD * DD * 2;
    unsigned short* w5t  = (unsigned short*)(ws + off); off += (size_t)5 * DD * DD * 2;
    unsigned short* w7t  = (unsigned short*)(ws + off); off += (size_t)7 * DD * DD * 2;
    unsigned short* w1t  = (unsigned short*)(ws + off); off += (size_t)DD * HID * 2;
    unsigned short* w2t  = (unsigned short*)(ws + off); off += (size_t)DD * HID * 2;
    int* srcp3 = (int*)(ws + off); off += (size_t)PTOT * 3 * 4;
    int* srcp5 = (int*)(ws + off); off += (size_t)PTOT * 5 * 4;
    int* srcp7 = (int*)(ws + off); off += (size_t)PTOT * 7 * 4;
    unsigned short* zp = (unsigned short*)(ws + off); off += 256;
    size_t base_off = off;
    bool full = (ws_size >= base_off + (size_t)PTOT * HID * 2);
    unsigned short* Hb = (unsigned short*)(ws + base_off);  // 32MB chunked / 128MB full

    // prep
    convert_x<<<PTOT * DD / (256 * 4), 256, 0, stream>>>(x, Xb, zp);
    trans_wconv<<<(DD * DD * 3 + 255) / 256, 256, 0, stream>>>(W3, w3t, 3);
    trans_wconv<<<(DD * DD * 5 + 255) / 256, 256, 0, stream>>>(W5, w5t, 5);
    trans_wconv<<<(DD * DD * 7 + 255) / 256, 256, 0, stream>>>(W7, w7t, 7);
    trans_w1<<<DD * HID / 256, 256, 0, stream>>>(w1, w1t);
    trans_w2<<<DD * HID / 256, 256, 0, stream>>>(w2, w2t);
    make_srcp<<<(PTOT * 3 + 255) / 256, 256, 0, stream>>>(chain, srcp3, 3);
    make_srcp<<<(PTOT * 5 + 255) / 256, 256, 0, stream>>>(chain, srcp5, 5);
    make_srcp<<<(PTOT * 7 + 255) / 256, 256, 0, stream>>>(chain, srcp7, 7);

    dim3 gconv(PTOT / 256, DD / 256);   // 128 x 2 = 256 blocks (1/CU)

    mfma_gemm8<3, 0><<<gconv, 512, 0, stream>>>(Xb, DD, srcp3, w3t, 3 * DD, b3, buf1, DD, DD, zp);
    mfma_gemm8<5, 0><<<gconv, 512, 0, stream>>>(buf1, DD, srcp5, w5t, 5 * DD, b5, buf2, DD, DD, zp);
    mfma_gemm8<7, 0><<<gconv, 512, 0, stream>>>(buf2, DD, srcp7, w7t, 7 * DD, b7, buf1, DD, DD, zp);

    ln1_kernel<<<PTOT, 256, 0, stream>>>(x, buf1, g1, be1, buf2);

    if (full) {
        dim3 g1d(PTOT / 256, HID / 256);   // 128 x 8
        mfma_gemm8<0, 1><<<g1d, 512, 0, stream>>>(buf2, DD, nullptr, w1t, DD, bm1,
                                                  Hb, HID, DD, zp);
        mfma_gemm8<0, 2><<<gconv, 512, 0, stream>>>(Hb, HID, nullptr, w2t, HID, bm2,
                                                    out, DD, HID, zp);
    } else {
        for (int jc = 0; jc < 4; jc++) {
            mfma_gemm8<0, 1><<<gconv, 512, 0, stream>>>(buf2, DD, nullptr,
                                                        w1t + (size_t)jc * DD * DD, DD,
                                                        bm1 + jc * DD, Hb, DD, DD, zp);
            if (jc == 0)
                mfma_gemm8<0, 2><<<gconv, 512, 0, stream>>>(Hb, DD, nullptr,
                                                            w2t + jc * DD, HID, bm2,
                                                            out, DD, DD, zp);
            else
                mfma_gemm8<0, 3><<<gconv, 512, 0, stream>>>(Hb, DD, nullptr,
                                                            w2t + jc * DD, HID, bm2,
                                                            out, DD, DD, zp);
        }
    }

    ln2_kernel<<<PTOT, 256, 0, stream>>>(buf2, out, g2, be2);
}

// Round 11
// 639.352 us; speedup vs baseline: 1.0531x; 1.0531x over previous
//
#include <hip/hip_runtime.h>
#include <math.h>

#define BB 8
#define LL 4096
#define DD 512
#define PTOT (BB*LL)      // 32768 positions
#define HID  2048

typedef __attribute__((ext_vector_type(8))) short short8;   // 8 bf16 (4 VGPRs)
typedef __attribute__((ext_vector_type(4))) float f32x4;

typedef __attribute__((address_space(1))) const unsigned int gconst_u32;
typedef __attribute__((address_space(3))) unsigned int lds_u32;

__device__ __forceinline__ void gload16(const void* g, void* l) {
    // async global->LDS DMA, 16B per lane; LDS dest = wave-uniform base + lane*16
    __builtin_amdgcn_global_load_lds((gconst_u32*)g, (lds_u32*)l, 16, 0, 0);
}

__device__ __forceinline__ unsigned short f2bf(float f) {
    union { float f; unsigned int u; } v; v.f = f;
    unsigned int r = v.u + 0x7fffu + ((v.u >> 16) & 1u);
    return (unsigned short)(r >> 16);
}
__device__ __forceinline__ float bf2f(unsigned short h) {
    union { unsigned int u; float f; } v; v.u = ((unsigned int)h) << 16;
    return v.f;
}
__device__ __forceinline__ float gelu_fast(float x) {
    float x2 = x * x;
    float t  = x * fmaf(0.044715f, x2, 1.0f);
    float e  = __builtin_amdgcn_exp2f(-2.3021143f * t);   // e^{-2z}
    return x * __builtin_amdgcn_rcpf(1.0f + e);
}

__device__ __forceinline__ void barrier_sync() {
    asm volatile("" ::: "memory");
    __builtin_amdgcn_s_barrier();
    asm volatile("" ::: "memory");
}
#define WAITV(N) asm volatile("s_waitcnt vmcnt(" #N ")" ::: "memory")
#define WAITL0() asm volatile("s_waitcnt lgkmcnt(0)" ::: "memory")
#define SCHED0() __builtin_amdgcn_sched_barrier(0)

// ---------------------------------------------------------------------------
// x fp32 -> bf16; also zero the 256B zero-page (ws is re-poisoned each launch)
__global__ __launch_bounds__(256) void convert_x(const float* __restrict__ x,
                                                 unsigned short* __restrict__ xb,
                                                 unsigned short* __restrict__ zp) {
    int tid = blockIdx.x * 256 + threadIdx.x;
    if (blockIdx.x == 0 && threadIdx.x < 128) zp[threadIdx.x] = 0;
    float4 v = ((const float4*)x)[tid];
    uint2 o;
    o.x = (unsigned int)f2bf(v.x) | ((unsigned int)f2bf(v.y) << 16);
    o.y = (unsigned int)f2bf(v.z) | ((unsigned int)f2bf(v.w) << 16);
    ((uint2*)xb)[tid] = o;
}

// conv W (o,c,k) -> Wt[o][k*512+c] bf16
__global__ __launch_bounds__(256) void trans_wconv(const float* __restrict__ W,
                                                   unsigned short* __restrict__ Wt, int K) {
    int tid = blockIdx.x * 256 + threadIdx.x;
    if (tid >= DD * DD * K) return;
    int o  = tid / (K * DD);
    int kc = tid - o * K * DD;
    int k  = kc >> 9;
    int c  = kc & (DD - 1);
    Wt[tid] = f2bf(W[(o * DD + c) * K + k]);
}

// mlp_w1 (c, n) -> W1t[n][c]
__global__ __launch_bounds__(256) void trans_w1(const float* __restrict__ W,
                                                unsigned short* __restrict__ Wt) {
    int tid = blockIdx.x * 256 + threadIdx.x;   // n*512 + c
    int n = tid >> 9;
    int c = tid & (DD - 1);
    Wt[tid] = f2bf(W[c * HID + n]);
}

// mlp_w2 (h, n) -> W2t[n][h]
__global__ __launch_bounds__(256) void trans_w2(const float* __restrict__ W,
                                                unsigned short* __restrict__ Wt) {
    int tid = blockIdx.x * 256 + threadIdx.x;   // n*2048 + h
    int n = tid >> 11;
    int h = tid & (HID - 1);
    Wt[tid] = f2bf(W[h * DD + n]);
}

// srcp[p*K + k] = p + k - pad if in-range and chain matches, else -1
__global__ __launch_bounds__(256) void make_srcp(const int* __restrict__ chain,
                                                 int* __restrict__ srcp, int K) {
    int tid = blockIdx.x * 256 + threadIdx.x;
    if (tid >= PTOT * K) return;
    int p = tid / K;
    int k = tid - p * K;
    int b = p >> 12;
    int l = p & (LL - 1);
    int pad = (K - 1) >> 1;
    int l2 = l + k - pad;
    bool ok = (l2 >= 0) && (l2 < LL) && (chain[b * LL + l2] == chain[b * LL + l]);
    srcp[tid] = ok ? (p + k - pad) : -1;
}

// ---------------------------------------------------------------------------
// 256x256 MFMA GEMM, 2 super-phases per K-tile (verified r7, 652.7us).
// 512 threads = 8 waves (2M x 4N), wave tile 128x64, BK=64, dbuf LDS 128KB.
// Phase discipline: RD -> STG -> lgkmcnt(0) -> sched_barrier(0) -> setprio
// MFMA -> barrier. RD MUST precede STG (gload16 is LDS-writing; STG-first
// forces conservative vmcnt ordering = round-6 regression). The vmcnt stream
// is PURE global_load_lds (no VGPR loads mixed in) -- round-10's mixed-type
// counted gates failed correctness; do not mix.
//   P1: read A0(8)+B0(4)+B1(4) | stage A1(kt+1),B1(kt+1) | MFMA (0,0),(0,1)
//   P2: read A1(8)             | stage A0(kt+2),B0(kt+2) | MFMA (1,0),(1,1)
// Overwrite safety: A1: rd P2(kt) -> iss P1(kt+1) = +1 bar; B1: rd P1(kt) ->
// iss P1(kt+1) = +2; A0,B0: rd P1/P2(kt) -> iss P2(kt) = +1 (reads drained by
// the mid-phase lgkmcnt(0) before each barrier).
// Counted vmcnt: WAITV(4) at end-P2(kt) leaves exactly A0,B0(kt+2) in flight
// => streams <=4kt+7 landed = tile kt+1's full needs. WAITV(0) at kt=NKT-2
// (its P2 stages clip on h>=4NKT). Last tile: no staging.
// EPI: 0 bf16=acc+bias; 1 bf16=gelu(acc+bias); 2 f32=acc+bias; 3 f32+=acc.
template <int TAPS, int EPI>
__global__ __launch_bounds__(512) void mfma_gemm6(
        const unsigned short* __restrict__ A, int lda,
        const int* __restrict__ srcp,
        const unsigned short* __restrict__ Bt, int ldb,
        const float* __restrict__ bias,
        void* __restrict__ Yv, int ldc, int Kspan,
        const unsigned short* __restrict__ zp) {
    __shared__ alignas(16) unsigned short As[2 * 256 * 64];   // 64 KB
    __shared__ alignas(16) unsigned short Bs[2 * 256 * 64];   // 64 KB
    __shared__ int srcp_s[TAPS > 0 ? 256 * TAPS : 4];         // <=7 KB

    const int t = threadIdx.x;
    const int lane = t & 63, w = t >> 6;
    const int wr = w & 1, wc = w >> 1;          // 2M x 4N waves
    const int lm = lane & 15, qh = lane >> 4, x7 = lane & 7;
    const int qq = (lane & 7) ^ (lane >> 3);    // staged source quad (swizzle)
    const int l3 = lane >> 3;                   // row-within-8
    const int p0 = blockIdx.x * 256;
    const int o0 = blockIdx.y * 256;
    const int NKT = TAPS ? TAPS * 8 : (Kspan >> 6);

    f32x4 acc[8][4];
#pragma unroll
    for (int mi = 0; mi < 8; mi++)
#pragma unroll
        for (int nj = 0; nj < 4; nj++) acc[mi][nj] = (f32x4){0.f, 0.f, 0.f, 0.f};

    // stream h: tile jt=h>>2 (buffer jt&1); h&1: 0=A,1=B; h&2: row half
    auto stgB = [&](int h) {
        if (h >= 4 * NKT) return;
        int jt = h >> 2;
        int rb = (h & 2) ? 128 : 0;
        unsigned short* dst = Bs + (jt & 1) * 16384 + (rb + w * 16) * 64;
        int kb = jt << 6;
#pragma unroll
        for (int i = 0; i < 2; i++) {
            int rl = rb + w * 16 + i * 8 + l3;
            gload16(Bt + (size_t)(o0 + rl) * ldb + kb + qq * 8, dst + i * 512);
        }
    };
    auto stgA = [&](int h, int sp0, int sp1) {
        if (h >= 4 * NKT) return;
        int jt = h >> 2;
        int rb = (h & 2) ? 128 : 0;
        unsigned short* dst = As + (jt & 1) * 16384 + (rb + w * 16) * 64;
#pragma unroll
        for (int i = 0; i < 2; i++) {
            const unsigned short* g;
            if (TAPS) {
                int sp = i ? sp1 : sp0;
                g = (sp >= 0) ? (A + (size_t)sp * lda + (jt & 7) * 64 + qq * 8) : zp;
            } else {
                int rl = rb + w * 16 + i * 8 + l3;
                g = A + (size_t)(p0 + rl) * lda + (jt << 6) + qq * 8;
            }
            gload16(g, dst + i * 512);
        }
    };
    auto ldsp = [&](int h, int& sp0, int& sp1) {   // prefetch gather rows for A-stream h
        if (TAPS && h < 4 * NKT) {
            int jt = h >> 2, tap = jt >> 3;
            int rb = (h & 2) ? 128 : 0;
            int rl = rb + w * 16 + l3;
            sp0 = srcp_s[rl * TAPS + tap];
            sp1 = srcp_s[(rl + 8) * TAPS + tap];
        }
    };

    // prologue
    if (TAPS) {
        for (int idx = t; idx < 256 * TAPS; idx += 512)
            srcp_s[idx] = srcp[(size_t)p0 * TAPS + idx];
    }
    __syncthreads();
    int sp0 = -1, sp1 = -1;
    ldsp(0, sp0, sp1); stgA(0, sp0, sp1);
    stgB(1);
    ldsp(2, sp0, sp1); stgA(2, sp0, sp1);
    stgB(3);
    ldsp(4, sp0, sp1); stgA(4, sp0, sp1);
    stgB(5);
    ldsp(6, sp0, sp1);                     // sp for tile0 P1's stgA(6)
    WAITV(4);                              // streams 0..3 (tile0) landed
    barrier_sync();

#define RD_A(MIH) do {                                                          \
    _Pragma("unroll")                                                           \
    for (int kk = 0; kk < 2; kk++) {                                            \
        int sa = ((kk * 4 + qh) ^ x7) * 8;                                      \
        _Pragma("unroll")                                                       \
        for (int m = 0; m < 4; m++)                                             \
            af[m][kk] = *(const short8*)&as_[((((MIH)*4+m)*2 + wr)*16 + lm)*64 + sa]; \
    } } while (0)
#define RD_B(NJH, BF) do {                                                      \
    _Pragma("unroll")                                                           \
    for (int kk = 0; kk < 2; kk++) {                                            \
        int sa = ((kk * 4 + qh) ^ x7) * 8;                                      \
        _Pragma("unroll")                                                       \
        for (int n = 0; n < 2; n++)                                             \
            BF[n][kk] = *(const short8*)&bs_[((((NJH)*2+n)*4 + wc)*16 + lm)*64 + sa]; \
    } } while (0)
#define MFMA_Q(MIH, NJH, BF)                                                    \
    __builtin_amdgcn_s_setprio(1);                                              \
    _Pragma("unroll")                                                           \
    for (int kk = 0; kk < 2; kk++)                                              \
        _Pragma("unroll")                                                       \
        for (int m = 0; m < 4; m++)                                             \
            _Pragma("unroll")                                                   \
            for (int n = 0; n < 2; n++)                                         \
                acc[(MIH)*4+m][(NJH)*2+n] = __builtin_amdgcn_mfma_f32_16x16x32_bf16( \
                    af[m][kk], BF[n][kk], acc[(MIH)*4+m][(NJH)*2+n], 0, 0, 0);  \
    __builtin_amdgcn_s_setprio(0)

    short8 af[4][2], bf0[2][2], bf1[2][2];
#pragma unroll 1
    for (int kt = 0; kt < NKT; ++kt) {
        const unsigned short* as_ = As + (kt & 1) * 16384;
        const unsigned short* bs_ = Bs + (kt & 1) * 16384;
        const bool last = (kt == NKT - 1);
        // ---- P1: read A0+B0+B1 | stage A1(kt+1),B1(kt+1) | mfma (0,0),(0,1)
        RD_A(0); RD_B(0, bf0); RD_B(1, bf1);
        if (!last) { stgA(4 * kt + 6, sp0, sp1); stgB(4 * kt + 7); }
        WAITL0(); SCHED0();
        MFMA_Q(0, 0, bf0);
        MFMA_Q(0, 1, bf1);
        if (!last) ldsp(4 * kt + 8, sp0, sp1);   // sp for P2's stgA
        barrier_sync();
        // ---- P2: read A1 | stage A0(kt+2),B0(kt+2) | mfma (1,0),(1,1) | vmcnt
        RD_A(1);
        if (!last) { stgA(4 * kt + 8, sp0, sp1); stgB(4 * kt + 9); }
        WAITL0(); SCHED0();
        MFMA_Q(1, 0, bf0);
        MFMA_Q(1, 1, bf1);
        if (!last) ldsp(4 * kt + 10, sp0, sp1);  // sp for next P1's stgA
        if (kt == NKT - 2) { WAITV(0); } else if (!last) { WAITV(4); }
        barrier_sync();
    }
#undef RD_A
#undef RD_B
#undef MFMA_Q

    // epilogue: C/D layout col=lane&15, row=(lane>>4)*4+reg  [m89-verified]
#pragma unroll
    for (int mi = 0; mi < 8; mi++) {
#pragma unroll
        for (int nj = 0; nj < 4; nj++) {
            int col = o0 + (nj * 4 + wc) * 16 + lm;
#pragma unroll
            for (int r = 0; r < 4; r++) {
                int row = p0 + (mi * 2 + wr) * 16 + qh * 4 + r;
                float v = acc[mi][nj][r];
                size_t idx = (size_t)row * ldc + col;
                if (EPI == 0) {
                    ((unsigned short*)Yv)[idx] = f2bf(v + bias[col]);
                } else if (EPI == 1) {
                    ((unsigned short*)Yv)[idx] = f2bf(gelu_fast(v + bias[col]));
                } else if (EPI == 2) {
                    ((float*)Yv)[idx] = v + bias[col];
                } else {
                    ((float*)Yv)[idx] += v;
                }
            }
        }
    }
}

// ---------------------------------------------------------------------------
// LN1: out_bf16 = LN(x_f32 + conv_bf16); vectorized: thread t owns cols 2t,2t+1
__global__ __launch_bounds__(256) void ln1_kernel(const float* __restrict__ x,
                                                  const unsigned short* __restrict__ conv,
                                                  const float* __restrict__ g,
                                                  const float* __restrict__ beta,
                                                  unsigned short* __restrict__ h) {
    int p = blockIdx.x, t = threadIdx.x;
    size_t base = (size_t)p * DD;
    float2 xv = ((const float2*)(x + base))[t];
    unsigned int cv = ((const unsigned int*)(conv + base))[t];
    float v0 = xv.x + bf2f((unsigned short)(cv & 0xffff));
    float v1 = xv.y + bf2f((unsigned short)(cv >> 16));
    float s = v0 + v1, sq = v0 * v0 + v1 * v1;
#pragma unroll
    for (int off = 32; off > 0; off >>= 1) { s += __shfl_xor(s, off); sq += __shfl_xor(sq, off); }
    __shared__ float red[2][4];
    int wid = t >> 6, lane = t & 63;
    if (lane == 0) { red[0][wid] = s; red[1][wid] = sq; }
    __syncthreads();
    float S = red[0][0] + red[0][1] + red[0][2] + red[0][3];
    float SQ = red[1][0] + red[1][1] + red[1][2] + red[1][3];
    float mu = S * (1.f / DD);
    float var = SQ * (1.f / DD) - mu * mu;
    float rs = rsqrtf(var + 1e-5f);
    float2 gv = ((const float2*)g)[t];
    float2 bv = ((const float2*)beta)[t];
    unsigned int o0 = f2bf((v0 - mu) * rs * gv.x + bv.x);
    unsigned int o1 = f2bf((v1 - mu) * rs * gv.y + bv.y);
    ((unsigned int*)(h + base))[t] = o0 | (o1 << 16);
}

// LN2: out_f32 = LN(h_bf16 + out_f32) in place; vectorized like LN1
__global__ __launch_bounds__(256) void ln2_kernel(const unsigned short* __restrict__ h,
                                                  float* __restrict__ out,
                                                  const float* __restrict__ g,
                                                  const float* __restrict__ beta) {
    int p = blockIdx.x, t = threadIdx.x;
    size_t base = (size_t)p * DD;
    float2 ov = ((const float2*)(out + base))[t];
    unsigned int hv = ((const unsigned int*)(h + base))[t];
    float v0 = bf2f((unsigned short)(hv & 0xffff)) + ov.x;
    float v1 = bf2f((unsigned short)(hv >> 16)) + ov.y;
    float s = v0 + v1, sq = v0 * v0 + v1 * v1;
#pragma unroll
    for (int off = 32; off > 0; off >>= 1) { s += __shfl_xor(s, off); sq += __shfl_xor(sq, off); }
    __shared__ float red[2][4];
    int wid = t >> 6, lane = t & 63;
    if (lane == 0) { red[0][wid] = s; red[1][wid] = sq; }
    __syncthreads();
    float S = red[0][0] + red[0][1] + red[0][2] + red[0][3];
    float SQ = red[1][0] + red[1][1] + red[1][2] + red[1][3];
    float mu = S * (1.f / DD);
    float var = SQ * (1.f / DD) - mu * mu;
    float rs = rsqrtf(var + 1e-5f);
    float2 gv = ((const float2*)g)[t];
    float2 bv = ((const float2*)beta)[t];
    float2 res;
    res.x = (v0 - mu) * rs * gv.x + bv.x;
    res.y = (v1 - mu) * rs * gv.y + bv.y;
    ((float2*)(out + base))[t] = res;
}

// ---------------------------------------------------------------------------
extern "C" void kernel_launch(void* const* d_in, const int* in_sizes, int n_in,
                              void* d_out, int out_size, void* d_ws, size_t ws_size,
                              hipStream_t stream) {
    const float* x     = (const float*)d_in[0];
    const int*   chain = (const int*)d_in[1];
    const float* W3    = (const float*)d_in[2];
    const float* b3    = (const float*)d_in[3];
    const float* W5    = (const float*)d_in[4];
    const float* b5    = (const float*)d_in[5];
    const float* W7    = (const float*)d_in[6];
    const float* b7    = (const float*)d_in[7];
    const float* w1    = (const float*)d_in[8];
    const float* bm1   = (const float*)d_in[9];
    const float* w2    = (const float*)d_in[10];
    const float* bm2   = (const float*)d_in[11];
    const float* g1    = (const float*)d_in[12];
    const float* be1   = (const float*)d_in[13];
    const float* g2    = (const float*)d_in[14];
    const float* be2   = (const float*)d_in[15];
    float* out = (float*)d_out;

    const size_t ACT = (size_t)PTOT * DD * 2;     // 32 MB bf16 activation buffer
    char* ws = (char*)d_ws;
    size_t off = 0;
    unsigned short* Xb   = (unsigned short*)(ws + off); off += ACT;
    unsigned short* buf1 = (unsigned short*)(ws + off); off += ACT;
    unsigned short* buf2 = (unsigned short*)(ws + off); off += ACT;
    unsigned short* w3t  = (unsigned short*)(ws + off); off += (size_t)3 * DD * DD * 2;
    unsigned short* w5t  = (unsigned short*)(ws + off); off += (size_t)5 * DD * DD * 2;
    unsigned short* w7t  = (unsigned short*)(ws + off); off += (size_t)7 * DD * DD * 2;
    unsigned short* w1t  = (unsigned short*)(ws + off); off += (size_t)DD * HID * 2;
    unsigned short* w2t  = (unsigned short*)(ws + off); off += (size_t)DD * HID * 2;
    int* srcp3 = (int*)(ws + off); off += (size_t)PTOT * 3 * 4;
    int* srcp5 = (int*)(ws + off); off += (size_t)PTOT * 5 * 4;
    int* srcp7 = (int*)(ws + off); off += (size_t)PTOT * 7 * 4;
    unsigned short* zp = (unsigned short*)(ws + off); off += 256;
    size_t base_off = off;
    bool full = (ws_size >= base_off + (size_t)PTOT * HID * 2);
    unsigned short* Hb = (unsigned short*)(ws + base_off);  // 128MB if full

    // prep
    convert_x<<<PTOT * DD / (256 * 4), 256, 0, stream>>>(x, Xb, zp);
    trans_wconv<<<(DD * DD * 3 + 255) / 256, 256, 0, stream>>>(W3, w3t, 3);
    trans_wconv<<<(DD * DD * 5 + 255) / 256, 256, 0, stream>>>(W5, w5t, 5);
    trans_wconv<<<(DD * DD * 7 + 255) / 256, 256, 0, stream>>>(W7, w7t, 7);
    trans_w1<<<DD * HID / 256, 256, 0, stream>>>(w1, w1t);
    trans_w2<<<DD * HID / 256, 256, 0, stream>>>(w2, w2t);
    make_srcp<<<(PTOT * 3 + 255) / 256, 256, 0, stream>>>(chain, srcp3, 3);
    make_srcp<<<(PTOT * 5 + 255) / 256, 256, 0, stream>>>(chain, srcp5, 5);
    make_srcp<<<(PTOT * 7 + 255) / 256, 256, 0, stream>>>(chain, srcp7, 7);

    dim3 gconv(PTOT / 256, DD / 256);   // 128 x 2 = 256 blocks (1/CU)

    mfma_gemm6<3, 0><<<gconv, 512, 0, stream>>>(Xb, DD, srcp3, w3t, 3 * DD, b3, buf1, DD, DD, zp);
    mfma_gemm6<5, 0><<<gconv, 512, 0, stream>>>(buf1, DD, srcp5, w5t, 5 * DD, b5, buf2, DD, DD, zp);
    mfma_gemm6<7, 0><<<gconv, 512, 0, stream>>>(buf2, DD, srcp7, w7t, 7 * DD, b7, buf1, DD, DD, zp);

    ln1_kernel<<<PTOT, 256, 0, stream>>>(x, buf1, g1, be1, buf2);
    // After LN1: Xb and buf1 are dead; they are CONTIGUOUS (ws+0 .. ws+64MB)
    // -> a free 64MB bf16 buffer = one HID/2=1024-wide H chunk.

    if (full) {
        dim3 g1d(PTOT / 256, HID / 256);   // 128 x 8
        mfma_gemm6<0, 1><<<g1d, 512, 0, stream>>>(buf2, DD, nullptr, w1t, DD, bm1,
                                                  Hb, HID, DD, zp);
        mfma_gemm6<0, 2><<<gconv, 512, 0, stream>>>(Hb, HID, nullptr, w2t, HID, bm2,
                                                    out, DD, HID, zp);
    } else {
        // 2-chunk MLP through Xb∪buf1 (vs old 4-chunk: out-traffic 448->192MB,
        // dispatches 8->4)
        unsigned short* H2 = Xb;           // 64 MB: PTOT x 1024 bf16
        dim3 gh(PTOT / 256, 1024 / 256);   // 128 x 4
        for (int jc = 0; jc < 2; jc++) {
            mfma_gemm6<0, 1><<<gh, 512, 0, stream>>>(buf2, DD, nullptr,
                                                     w1t + (size_t)jc * 1024 * DD, DD,
                                                     bm1 + jc * 1024, H2, 1024, DD, zp);
            if (jc == 0)
                mfma_gemm6<0, 2><<<gconv, 512, 0, stream>>>(H2, 1024, nullptr,
                                                            w2t + jc * 1024, HID, bm2,
                                                            out, DD, 1024, zp);
            else
                mfma_gemm6<0, 3><<<gconv, 512, 0, stream>>>(H2, 1024, nullptr,
                                                            w2t + jc * 1024, HID, bm2,
                                                            out, DD, 1024, zp);
        }
    }

    ln2_kernel<<<PTOT, 256, 0, stream>>>(buf2, out, g2, be2);
}